// Round 3
// baseline (509.260 us; speedup 1.0000x reference)
//
#include <hip/hip_runtime.h>
#include <math.h>

typedef __bf16 bf16x8 __attribute__((ext_vector_type(8)));
typedef __bf16 bf16x4 __attribute__((ext_vector_type(4)));
typedef float  f32x4  __attribute__((ext_vector_type(4)));

#define NTOK 4096
#define CDIM 1024
#define EEXP 8
#define IDIM 2048

__device__ __forceinline__ void async_copy16(const __bf16* g, __bf16* l) {
  __builtin_amdgcn_global_load_lds((const __attribute__((address_space(1))) void*)g,
                                   (__attribute__((address_space(3))) void*)l,
                                   16, 0, 0);
}

// tanh-form gelu: max abs dev from exact erf-gelu ~3e-4
__device__ __forceinline__ float gelu_f(float x) {
  float u = 0.7978845608028654f * fmaf(0.044715f * x * x, x, x);
  float ex = __expf(-2.f * fabsf(u));
  float th = copysignf((1.f - ex) / (1.f + ex), u);
  return 0.5f * x * (1.f + th);
}

// ---------------- gating + h->bf16 (one block per token; NO atomics) ----------------
__global__ __launch_bounds__(256) void gating_kernel(
    const float* __restrict__ h, const float* __restrict__ sim,
    const float* __restrict__ gates, const float* __restrict__ temp,
    const float* __restrict__ emask, const int* __restrict__ minexp,
    float* __restrict__ out_logits, float* __restrict__ out_act,
    float* __restrict__ inv_num, __bf16* __restrict__ hb)
{
  const int t = blockIdx.x, tid = threadIdx.x;
  float4 hv4 = ((const float4*)(h + (size_t)t * CDIM))[tid];
  float hv[4] = {hv4.x, hv4.y, hv4.z, hv4.w};
  bf16x4 hb4 = {(__bf16)hv[0], (__bf16)hv[1], (__bf16)hv[2], (__bf16)hv[3]};
  ((bf16x4*)(hb + (size_t)t * CDIM))[tid] = hb4;

  float d[EEXP], nn[EEXP];
  #pragma unroll
  for (int e = 0; e < EEXP; ++e) { d[e] = 0.f; nn[e] = 0.f; }
  float ss = 0.f;
  #pragma unroll
  for (int j = 0; j < 4; ++j) {
    ss = fmaf(hv[j], hv[j], ss);
    const float* sr = sim + (size_t)(tid * 4 + j) * EEXP;  // one sim row = 8 f32
    float4 s0 = ((const float4*)sr)[0];
    float4 s1 = ((const float4*)sr)[1];
    float sv[8] = {s0.x, s0.y, s0.z, s0.w, s1.x, s1.y, s1.z, s1.w};
    #pragma unroll
    for (int e = 0; e < EEXP; ++e) {
      d[e]  = fmaf(hv[j], sv[e], d[e]);
      nn[e] = fmaf(sv[e], sv[e], nn[e]);
    }
  }
  #pragma unroll
  for (int off = 32; off > 0; off >>= 1) {
    ss += __shfl_down(ss, off);
    #pragma unroll
    for (int e = 0; e < EEXP; ++e) {
      d[e]  += __shfl_down(d[e], off);
      nn[e] += __shfl_down(nn[e], off);
    }
  }
  __shared__ float red[4][20];
  const int wv = tid >> 6;
  if ((tid & 63) == 0) {
    red[wv][0] = ss;
    #pragma unroll
    for (int e = 0; e < EEXP; ++e) { red[wv][1 + e] = d[e]; red[wv][9 + e] = nn[e]; }
  }
  __syncthreads();
  if (tid == 0) {
    float sst = red[0][0] + red[1][0] + red[2][0] + red[3][0];
    float inv_h = 1.f / fmaxf(sqrtf(sst), 1e-12f);
    float ls = 1.f / (1.f + expf(-temp[0]));
    float logit[EEXP], act[EEXP];
    float cnt = 0.f;
    #pragma unroll
    for (int e = 0; e < EEXP; ++e) {
      float dot = red[0][1 + e] + red[1][1 + e] + red[2][1 + e] + red[3][1 + e];
      float nne = red[0][9 + e] + red[1][9 + e] + red[2][9 + e] + red[3][9 + e];
      float inv_s = 1.f / fmaxf(sqrtf(nne), 1e-12f);
      logit[e] = dot * inv_h * inv_s * emask[e];
      float g = logit[e] - gates[e] * ls;   // relu(x)>0 <=> x>0
      act[e] = (g > 0.f) ? 1.f : 0.f;
      cnt += act[e];
    }
    if (cnt == 0.f) {  // fallback: top-min_experts by logits (ties -> lowest index)
      int k = minexp[0];
      if (k > EEXP) k = EEXP;
      bool used[EEXP];
      #pragma unroll
      for (int e = 0; e < EEXP; ++e) used[e] = false;
      for (int j = 0; j < k; ++j) {
        int best = -1; float bv = 0.f;
        for (int e = 0; e < EEXP; ++e)
          if (!used[e] && (best < 0 || logit[e] > bv)) { best = e; bv = logit[e]; }
        if (best >= 0) { used[best] = true; act[best] = 1.f; cnt += 1.f; }
      }
    }
    float num = fmaxf(cnt, 1.f);
    inv_num[t] = 1.f / num;
    #pragma unroll
    for (int e = 0; e < EEXP; ++e) {
      out_logits[(size_t)t * EEXP + e] = logit[e];
      out_act[(size_t)t * EEXP + e]   = act[e];
    }
  }
}

// ---------------- pack: one wave per expert, ballot prefix scan (no atomics) ----------------
__global__ __launch_bounds__(64) void pack_kernel(
    const float* __restrict__ out_act, int* __restrict__ counts,
    unsigned short* __restrict__ perm)
{
  const int e = blockIdx.x;
  const int lane = threadIdx.x;
  const unsigned long long ltmask = (lane == 63) ? ~0ULL >> 1 : (1ULL << lane) - 1ULL;
  int base = 0;
  for (int i = 0; i < NTOK / 64; ++i) {
    int tok = i * 64 + lane;
    bool f = out_act[(size_t)tok * EEXP + e] > 0.f;
    unsigned long long m = __ballot(f);
    if (f) perm[e * NTOK + base + __popcll(m & ltmask)] = (unsigned short)tok;
    base += __popcll(m);
  }
  if (lane == 0) counts[e] = base;
}

// ---------------- fp32 64x64 tiled transpose+convert: out_bf16[c][r] = in_f32[r][c] ----------------
__global__ __launch_bounds__(256) void transpose_f32_bf16(
    const float* __restrict__ in0, __bf16* __restrict__ out0, int R, int Cc,
    long sIn, long sOut)
{
  const float* in = in0 + (size_t)blockIdx.z * sIn;
  __bf16* out = out0 + (size_t)blockIdx.z * sOut;
  __shared__ __align__(16) __bf16 tile[64][72];
  const int tid = threadIdx.x;
  const int c0 = blockIdx.x * 64, r0 = blockIdx.y * 64;
  #pragma unroll
  for (int p = 0; p < 2; ++p) {
    int lin = p * 256 + tid;
    int r = lin >> 3, c8 = (lin & 7) * 8;
    const float* src = in + (size_t)(r0 + r) * Cc + c0 + c8;
    float4 v0 = ((const float4*)src)[0];
    float4 v1 = ((const float4*)src)[1];
    bf16x8 v = {(__bf16)v0.x, (__bf16)v0.y, (__bf16)v0.z, (__bf16)v0.w,
                (__bf16)v1.x, (__bf16)v1.y, (__bf16)v1.z, (__bf16)v1.w};
    *(bf16x8*)&tile[r][c8] = v;
  }
  __syncthreads();
  #pragma unroll
  for (int p = 0; p < 2; ++p) {
    int lin = p * 256 + tid;
    int oc = lin >> 3, j8 = (lin & 7) * 8;
    bf16x8 o;
    #pragma unroll
    for (int jj = 0; jj < 8; ++jj) o[jj] = tile[j8 + jj][oc];
    *(bf16x8*)(out + (size_t)(c0 + oc) * R + r0 + j8) = o;
  }
}

// ---------------- 256x256-tile 8-wave packed GEMM, ring-4 K=32-slice pipeline ----------------
// T3+T4: 2 phases/slice, 1 half-slice global_load_lds prefetch per phase staged 2 slices
// ahead; counted s_waitcnt vmcnt(4) once per slice (never 0 in main loop).
// T2: chunk-XOR LDS swizzle (linear gload-lds dest + inverse-swizzled SOURCE + swizzled read).
// T5: s_setprio(1) around each 16-MFMA cluster.
// T1: XCD-aware block decode: all m-blocks of one (expert, n-panel) share h%8 -> same XCD L2.
// MODE 0 (gemm1): A = hb gathered via perm[e]; epilogue gelu*inv_num -> bf16 inter_pk[e]
// MODE 1 (gemm2): A = inter_pk[e] packed rows; epilogue atomicAdd scatter to out f32 by token
template <int MODE, int NN, int KK, int NB>
__global__ __launch_bounds__(512, 2) void gemm_pk(
    const __bf16* __restrict__ A0, const __bf16* __restrict__ B0,
    const int* __restrict__ counts, const unsigned short* __restrict__ perm,
    const float* __restrict__ inv_num, void* __restrict__ Cout)
{
  // XCD-aware decode: h = xr + 8*(g*16 + mb), panel = g*8 + xr -> (e, nb)
  const int hid = blockIdx.x;
  const int xr = hid & 7, q = hid >> 3;
  const int mb = q & 15;
  const int panel = ((q >> 4) << 3) + xr;
  const int e = panel / NB;
  const int nb = panel - e * NB;
  const int Me = counts[e];
  const int m0 = mb * 256;
  if (m0 >= Me) return;                       // block-uniform, before any barrier
  const int n0 = nb * 256;

  const int tid = threadIdx.x;
  const int wave = tid >> 6, lane = tid & 63;
  const int wr = wave >> 2, wc = wave & 3;    // 2M x 4N wave grid; wave owns 128x64
  const int quad = lane >> 4, lrow = lane & 15;
  // read-side swizzle: logical k-chunk quad lives at physical chunk quad^(row&3)
  const int axk = ((quad ^ (lrow & 3)) << 3);

  // ring of 4 K=32 slices; each slice: A[256][32] + B[256][32] bf16 = 32KB. total 128KB
  __shared__ __align__(16) __bf16 lds[4 * 16384];
  #define LDSA(j) (lds + (((j) & 3) << 14))
  #define LDSB(j) (lds + (((j) & 3) << 14) + 8192)

  // staging: per call 512 thr x 16B = 8KB = rows [base,base+128) of one region.
  // thread covers row lr, physical chunk tid&3 -> source logical chunk ch = (tid&3)^(lr&3)
  const int lr = tid >> 2;
  const int ch = ((tid & 3) ^ (lr & 3)) << 3;   // element offset in row
  const unsigned short* pe = perm + e * NTOK;
  const __bf16 *aS0, *aS1;
  if (MODE == 0) {
    aS0 = A0 + (size_t)pe[min(m0 + lr, Me - 1)] * KK + ch;
    aS1 = A0 + (size_t)pe[min(m0 + 128 + lr, Me - 1)] * KK + ch;
  } else {
    const __bf16* Ab = A0 + (size_t)e * NTOK * KK;
    aS0 = Ab + (size_t)(m0 + lr) * KK + ch;
    aS1 = Ab + (size_t)(m0 + 128 + lr) * KK + ch;
  }
  const __bf16* Bb = B0 + (size_t)e * ((size_t)CDIM * IDIM);
  const __bf16* bS0 = Bb + (size_t)(n0 + lr) * KK + ch;
  const __bf16* bS1 = Bb + (size_t)(n0 + 128 + lr) * KK + ch;

  f32x4 acc[8][4] = {};
  constexpr int NS = KK / 32;

  // prologue: stage slices 0 and 1 (4 loads each); wait slice 0 (counted), barrier
  async_copy16(aS0,      LDSA(0) + wave * 512);
  async_copy16(aS1,      LDSA(0) + 4096 + wave * 512);
  async_copy16(bS0,      LDSB(0) + wave * 512);
  async_copy16(bS1,      LDSB(0) + 4096 + wave * 512);
  async_copy16(aS0 + 32, LDSA(1) + wave * 512);
  async_copy16(aS1 + 32, LDSA(1) + 4096 + wave * 512);
  async_copy16(bS0 + 32, LDSB(1) + wave * 512);
  async_copy16(bS1 + 32, LDSB(1) + 4096 + wave * 512);
  asm volatile("s_waitcnt vmcnt(4)" ::: "memory");
  __builtin_amdgcn_s_barrier();

  const int arow = (wr << 7) + lrow;          // + mi*16 (+64 for phase 1)
  const int brow = (wc << 6) + lrow;

  for (int s = 0; s < NS; ++s) {
    const __bf16* Asl = LDSA(s);
    const __bf16* Bsl = LDSB(s);
    bf16x8 af[4], bfr[4];
    // ---- phase 0: C-half 0 (m-frags 0..3), stage A of slice s+2 ----
    #pragma unroll
    for (int mi = 0; mi < 4; ++mi)
      af[mi] = *(const bf16x8*)(Asl + ((arow + mi * 16) << 5) + axk);
    #pragma unroll
    for (int ni = 0; ni < 4; ++ni)
      bfr[ni] = *(const bf16x8*)(Bsl + ((brow + ni * 16) << 5) + axk);
    if (s + 2 < NS) {
      async_copy16(aS0 + (s + 2) * 32, LDSA(s + 2) + wave * 512);
      async_copy16(aS1 + (s + 2) * 32, LDSA(s + 2) + 4096 + wave * 512);
    }
    __builtin_amdgcn_s_barrier();
    __builtin_amdgcn_s_setprio(1);
    #pragma unroll
    for (int mi = 0; mi < 4; ++mi)
      #pragma unroll
      for (int ni = 0; ni < 4; ++ni)
        acc[mi][ni] = __builtin_amdgcn_mfma_f32_16x16x32_bf16(af[mi], bfr[ni], acc[mi][ni], 0, 0, 0);
    __builtin_amdgcn_s_setprio(0);
    __builtin_amdgcn_s_barrier();
    // ---- phase 1: C-half 1 (m-frags 4..7), stage B of slice s+2; slice-end vmcnt ----
    #pragma unroll
    for (int mi = 0; mi < 4; ++mi)
      af[mi] = *(const bf16x8*)(Asl + ((arow + 64 + mi * 16) << 5) + axk);
    if (s + 2 < NS) {
      async_copy16(bS0 + (s + 2) * 32, LDSB(s + 2) + wave * 512);
      async_copy16(bS1 + (s + 2) * 32, LDSB(s + 2) + 4096 + wave * 512);
    }
    __builtin_amdgcn_s_barrier();
    __builtin_amdgcn_s_setprio(1);
    #pragma unroll
    for (int mi = 0; mi < 4; ++mi)
      #pragma unroll
      for (int ni = 0; ni < 4; ++ni)
        acc[4 + mi][ni] = __builtin_amdgcn_mfma_f32_16x16x32_bf16(af[mi], bfr[ni], acc[4 + mi][ni], 0, 0, 0);
    __builtin_amdgcn_s_setprio(0);
    if (s + 2 < NS)      { asm volatile("s_waitcnt vmcnt(4)" ::: "memory"); }  // slice s+1 landed
    else if (s + 1 < NS) { asm volatile("s_waitcnt vmcnt(0)" ::: "memory"); }  // epilogue drain
    __builtin_amdgcn_s_barrier();
  }
  #undef LDSA
  #undef LDSB

  if (MODE == 0) {
    __bf16* O = (__bf16*)Cout + (size_t)e * NTOK * NN;
    #pragma unroll
    for (int mi = 0; mi < 8; ++mi) {
      #pragma unroll
      for (int r = 0; r < 4; ++r) {
        const int row = m0 + (wr << 7) + mi * 16 + (quad << 2) + r;   // packed row, < 4096
        const float sv = inv_num[pe[min(row, Me - 1)]];
        #pragma unroll
        for (int ni = 0; ni < 4; ++ni) {
          const int col = n0 + (wc << 6) + ni * 16 + lrow;
          O[(size_t)row * NN + col] = (__bf16)(gelu_f(acc[mi][ni][r]) * sv);
        }
      }
    }
  } else {
    float* O = (float*)Cout;
    #pragma unroll
    for (int mi = 0; mi < 8; ++mi) {
      #pragma unroll
      for (int r = 0; r < 4; ++r) {
        const int row = m0 + (wr << 7) + mi * 16 + (quad << 2) + r;
        if (row < Me) {
          const int tok = pe[row];
          #pragma unroll
          for (int ni = 0; ni < 4; ++ni) {
            const int col = n0 + (wc << 6) + ni * 16 + lrow;
            atomicAdd(&O[(size_t)tok * NN + col], acc[mi][ni][r]);
          }
        }
      }
    }
  }
}

extern "C" void kernel_launch(void* const* d_in, const int* in_sizes, int n_in,
                              void* d_out, int out_size, void* d_ws, size_t ws_size,
                              hipStream_t stream) {
  (void)in_sizes; (void)n_in; (void)out_size; (void)ws_size;
  const float* h     = (const float*)d_in[0];
  const float* sim   = (const float*)d_in[1];
  const float* gates = (const float*)d_in[2];
  const float* temp  = (const float*)d_in[3];
  const float* emask = (const float*)d_in[4];
  const float* w1    = (const float*)d_in[5];
  const float* w2    = (const float*)d_in[6];
  const int*   minexp = (const int*)d_in[7];

  float* out_final  = (float*)d_out;                        // [4096][1024]
  float* out_logits = out_final + (size_t)NTOK * CDIM;      // [4096][8]
  float* out_act    = out_logits + (size_t)NTOK * EEXP;     // [4096][8]

  char* ws = (char*)d_ws;                                   // ~200.1 MB used (ws >= 209846528 proven r3)
  float*          inv_num  = (float*)(ws + 0);              // [4096] f32 (16KB)
  int*            counts   = (int*)(ws + 16384);            // [8] i32
  unsigned short* perm     = (unsigned short*)(ws + 16448); // [8][4096] u16 (64KB)
  __bf16*         hb       = (__bf16*)(ws + 81984);         // [4096][1024] bf16 (8MB)
  __bf16*         w1T_all  = (__bf16*)(ws + 8470592);       // [E][2048][1024] bf16 (32MB)
  __bf16*         w2T_all  = (__bf16*)(ws + 42025024);      // [E][1024][2048] bf16 (32MB)
  __bf16*         inter_pk = (__bf16*)(ws + 75579456);      // [E][4096][2048] bf16 (128MB)

  const long sW = (long)CDIM * IDIM;

  hipMemsetAsync(out_final, 0, (size_t)NTOK * CDIM * sizeof(float), stream);
  // w1[e]: [C][I] f32 -> w1T [I][C] bf16;  w2[e]: [I][C] f32 -> w2T [C][I] bf16
  transpose_f32_bf16<<<dim3(IDIM / 64, CDIM / 64, EEXP), 256, 0, stream>>>(
      w1, w1T_all, CDIM, IDIM, sW, sW);
  transpose_f32_bf16<<<dim3(CDIM / 64, IDIM / 64, EEXP), 256, 0, stream>>>(
      w2, w2T_all, IDIM, CDIM, sW, sW);
  gating_kernel<<<NTOK, 256, 0, stream>>>(h, sim, gates, temp, emask, minexp,
                                          out_logits, out_act, inv_num, hb);
  pack_kernel<<<EEXP, 64, 0, stream>>>(out_act, counts, perm);
  // gemm1 (packed, 256^2 8-phase): inter_pk[e][0..Me) = gelu(hb[perm] @ w1[e]) * inv_num[perm]
  gemm_pk<0, IDIM, CDIM, IDIM / 256><<<dim3((IDIM / 256) * (NTOK / 256) * EEXP), 512, 0, stream>>>(
      hb, w1T_all, counts, perm, inv_num, (void*)inter_pk);
  // gemm2 (packed, 256^2 8-phase): out[perm] += inter_pk[e] @ w2[e]
  gemm_pk<1, CDIM, IDIM, CDIM / 256><<<dim3((CDIM / 256) * (NTOK / 256) * EEXP), 512, 0, stream>>>(
      inter_pk, w2T_all, counts, perm, inv_num, (void*)out_final);
}

// Round 4
// 500.448 us; speedup vs baseline: 1.0176x; 1.0176x over previous
//
#include <hip/hip_runtime.h>
#include <math.h>

typedef __bf16 bf16x8 __attribute__((ext_vector_type(8)));
typedef __bf16 bf16x4 __attribute__((ext_vector_type(4)));
typedef float  f32x4  __attribute__((ext_vector_type(4)));

#define NTOK 4096
#define CDIM 1024
#define EEXP 8
#define IDIM 2048

__device__ __forceinline__ void async_copy16(const __bf16* g, __bf16* l) {
  __builtin_amdgcn_global_load_lds((const __attribute__((address_space(1))) void*)g,
                                   (__attribute__((address_space(3))) void*)l,
                                   16, 0, 0);
}

// tanh-form gelu: max abs dev from exact erf-gelu ~3e-4
__device__ __forceinline__ float gelu_f(float x) {
  float u = 0.7978845608028654f * fmaf(0.044715f * x * x, x, x);
  float ex = __expf(-2.f * fabsf(u));
  float th = copysignf((1.f - ex) / (1.f + ex), u);
  return 0.5f * x * (1.f + th);
}

// ---------------- gating + h->bf16 (one block per token; NO atomics) ----------------
__global__ __launch_bounds__(256) void gating_kernel(
    const float* __restrict__ h, const float* __restrict__ sim,
    const float* __restrict__ gates, const float* __restrict__ temp,
    const float* __restrict__ emask, const int* __restrict__ minexp,
    float* __restrict__ out_logits, float* __restrict__ out_act,
    float* __restrict__ inv_num, __bf16* __restrict__ hb)
{
  const int t = blockIdx.x, tid = threadIdx.x;
  float4 hv4 = ((const float4*)(h + (size_t)t * CDIM))[tid];
  float hv[4] = {hv4.x, hv4.y, hv4.z, hv4.w};
  bf16x4 hb4 = {(__bf16)hv[0], (__bf16)hv[1], (__bf16)hv[2], (__bf16)hv[3]};
  ((bf16x4*)(hb + (size_t)t * CDIM))[tid] = hb4;

  float d[EEXP], nn[EEXP];
  #pragma unroll
  for (int e = 0; e < EEXP; ++e) { d[e] = 0.f; nn[e] = 0.f; }
  float ss = 0.f;
  #pragma unroll
  for (int j = 0; j < 4; ++j) {
    ss = fmaf(hv[j], hv[j], ss);
    const float* sr = sim + (size_t)(tid * 4 + j) * EEXP;  // one sim row = 8 f32
    float4 s0 = ((const float4*)sr)[0];
    float4 s1 = ((const float4*)sr)[1];
    float sv[8] = {s0.x, s0.y, s0.z, s0.w, s1.x, s1.y, s1.z, s1.w};
    #pragma unroll
    for (int e = 0; e < EEXP; ++e) {
      d[e]  = fmaf(hv[j], sv[e], d[e]);
      nn[e] = fmaf(sv[e], sv[e], nn[e]);
    }
  }
  #pragma unroll
  for (int off = 32; off > 0; off >>= 1) {
    ss += __shfl_down(ss, off);
    #pragma unroll
    for (int e = 0; e < EEXP; ++e) {
      d[e]  += __shfl_down(d[e], off);
      nn[e] += __shfl_down(nn[e], off);
    }
  }
  __shared__ float red[4][20];
  const int wv = tid >> 6;
  if ((tid & 63) == 0) {
    red[wv][0] = ss;
    #pragma unroll
    for (int e = 0; e < EEXP; ++e) { red[wv][1 + e] = d[e]; red[wv][9 + e] = nn[e]; }
  }
  __syncthreads();
  if (tid == 0) {
    float sst = red[0][0] + red[1][0] + red[2][0] + red[3][0];
    float inv_h = 1.f / fmaxf(sqrtf(sst), 1e-12f);
    float ls = 1.f / (1.f + expf(-temp[0]));
    float logit[EEXP], act[EEXP];
    float cnt = 0.f;
    #pragma unroll
    for (int e = 0; e < EEXP; ++e) {
      float dot = red[0][1 + e] + red[1][1 + e] + red[2][1 + e] + red[3][1 + e];
      float nne = red[0][9 + e] + red[1][9 + e] + red[2][9 + e] + red[3][9 + e];
      float inv_s = 1.f / fmaxf(sqrtf(nne), 1e-12f);
      logit[e] = dot * inv_h * inv_s * emask[e];
      float g = logit[e] - gates[e] * ls;   // relu(x)>0 <=> x>0
      act[e] = (g > 0.f) ? 1.f : 0.f;
      cnt += act[e];
    }
    if (cnt == 0.f) {  // fallback: top-min_experts by logits (ties -> lowest index)
      int k = minexp[0];
      if (k > EEXP) k = EEXP;
      bool used[EEXP];
      #pragma unroll
      for (int e = 0; e < EEXP; ++e) used[e] = false;
      for (int j = 0; j < k; ++j) {
        int best = -1; float bv = 0.f;
        for (int e = 0; e < EEXP; ++e)
          if (!used[e] && (best < 0 || logit[e] > bv)) { best = e; bv = logit[e]; }
        if (best >= 0) { used[best] = true; act[best] = 1.f; cnt += 1.f; }
      }
    }
    float num = fmaxf(cnt, 1.f);
    inv_num[t] = 1.f / num;
    #pragma unroll
    for (int e = 0; e < EEXP; ++e) {
      out_logits[(size_t)t * EEXP + e] = logit[e];
      out_act[(size_t)t * EEXP + e]   = act[e];
    }
  }
}

// ---------------- pack: one wave per expert, ballot prefix scan (no atomics) ----------------
__global__ __launch_bounds__(64) void pack_kernel(
    const float* __restrict__ out_act, int* __restrict__ counts,
    unsigned short* __restrict__ perm)
{
  const int e = blockIdx.x;
  const int lane = threadIdx.x;
  const unsigned long long ltmask = (lane == 63) ? ~0ULL >> 1 : (1ULL << lane) - 1ULL;
  int base = 0;
  for (int i = 0; i < NTOK / 64; ++i) {
    int tok = i * 64 + lane;
    bool f = out_act[(size_t)tok * EEXP + e] > 0.f;
    unsigned long long m = __ballot(f);
    if (f) perm[e * NTOK + base + __popcll(m & ltmask)] = (unsigned short)tok;
    base += __popcll(m);
  }
  if (lane == 0) counts[e] = base;
}

// ---------------- fp32 64x64 tiled transpose+convert: out_bf16[c][r] = in_f32[r][c] ----------------
__global__ __launch_bounds__(256) void transpose_f32_bf16(
    const float* __restrict__ in0, __bf16* __restrict__ out0, int R, int Cc,
    long sIn, long sOut)
{
  const float* in = in0 + (size_t)blockIdx.z * sIn;
  __bf16* out = out0 + (size_t)blockIdx.z * sOut;
  __shared__ __align__(16) __bf16 tile[64][72];
  const int tid = threadIdx.x;
  const int c0 = blockIdx.x * 64, r0 = blockIdx.y * 64;
  #pragma unroll
  for (int p = 0; p < 2; ++p) {
    int lin = p * 256 + tid;
    int r = lin >> 3, c8 = (lin & 7) * 8;
    const float* src = in + (size_t)(r0 + r) * Cc + c0 + c8;
    float4 v0 = ((const float4*)src)[0];
    float4 v1 = ((const float4*)src)[1];
    bf16x8 v = {(__bf16)v0.x, (__bf16)v0.y, (__bf16)v0.z, (__bf16)v0.w,
                (__bf16)v1.x, (__bf16)v1.y, (__bf16)v1.z, (__bf16)v1.w};
    *(bf16x8*)&tile[r][c8] = v;
  }
  __syncthreads();
  #pragma unroll
  for (int p = 0; p < 2; ++p) {
    int lin = p * 256 + tid;
    int oc = lin >> 3, j8 = (lin & 7) * 8;
    bf16x8 o;
    #pragma unroll
    for (int jj = 0; jj < 8; ++jj) o[jj] = tile[j8 + jj][oc];
    *(bf16x8*)(out + (size_t)(c0 + oc) * R + r0 + j8) = o;
  }
}

// ---------------- 256x256-tile 8-wave packed GEMM, BK=64 ring-2, 1 barrier/slice ----------------
// Post-r3 fix: (a) BK=64 -> 128B rows -> full 3-bit chunk^row XOR swizzle (2-way residual, free);
// (b) NO intra-slice barriers: ds_read/MFMA free-flow (compiler lgkmcnt), LDS and matrix pipes
// overlap; (c) all 8 stage calls for slice s+1 issued at TOP of slice s -> boundary vmcnt(0) is
// cold (~2400cyc slack > HBM latency). One vmcnt+barrier per slice.
// MODE 0 (gemm1): A = hb gathered via perm[e]; epilogue gelu*inv_num -> bf16 inter_pk[e]
// MODE 1 (gemm2): A = inter_pk[e] packed rows; epilogue atomicAdd scatter to out f32 by token
template <int MODE, int NN, int KK, int NB>
__global__ __launch_bounds__(512, 2) void gemm_pk(
    const __bf16* __restrict__ A0, const __bf16* __restrict__ B0,
    const int* __restrict__ counts, const unsigned short* __restrict__ perm,
    const float* __restrict__ inv_num, void* __restrict__ Cout)
{
  // XCD-aware decode: h = xr + 8*(g*16 + mb), panel = g*8 + xr -> (e, nb)
  const int hid = blockIdx.x;
  const int xr = hid & 7, q2 = hid >> 3;
  const int mb = q2 & 15;
  const int panel = ((q2 >> 4) << 3) + xr;
  const int e = panel / NB;
  const int nb = panel - e * NB;
  const int Me = counts[e];
  const int m0 = mb * 256;
  if (m0 >= Me) return;                       // block-uniform, before any barrier
  const int n0 = nb * 256;

  const int tid = threadIdx.x;
  const int wave = tid >> 6, lane = tid & 63;
  const int wr = wave >> 2, wc = wave & 3;    // 2M x 4N wave grid; wave owns 128x64
  const int quad = lane >> 4, lrow = lane & 15;
  // read swizzle: logical 16B-chunk kc lives at physical chunk kc ^ (row&7); row&7 == lrow&7
  const int sw0 = ((quad ^ (lrow & 7)) << 3);         // kh=0: kc = quad
  const int sw1 = (((4 + quad) ^ (lrow & 7)) << 3);   // kh=1: kc = 4+quad

  // ring-2 of BK=64 slices; slice = A[256][64] + B[256][64] bf16 = 64KB. total 128KB
  __shared__ __align__(16) __bf16 lds[2 * 32768];

  // staging: 8 calls/slice, each 512thr x 16B = 8KB = 64 rows x 128B.
  // thread -> row lr2 = tid>>3 (of 64-row group), phys chunk tid&7, source chunk ^(row&7)
  const int lr2 = tid >> 3;
  const int ch  = (((tid & 7) ^ (lr2 & 7)) << 3);   // elem offset in row (inverse-swizzled src)
  const unsigned short* pe = perm + e * NTOK;
  const __bf16* aP[4];
  const __bf16* bP[4];
  if (MODE == 0) {
    #pragma unroll
    for (int g = 0; g < 4; ++g)
      aP[g] = A0 + (size_t)pe[min(m0 + g * 64 + lr2, Me - 1)] * KK + ch;
  } else {
    const __bf16* Ab = A0 + (size_t)e * NTOK * KK;
    #pragma unroll
    for (int g = 0; g < 4; ++g)
      aP[g] = Ab + (size_t)(m0 + g * 64 + lr2) * KK + ch;
  }
  const __bf16* Bb = B0 + (size_t)e * ((size_t)CDIM * IDIM);
  #pragma unroll
  for (int g = 0; g < 4; ++g)
    bP[g] = Bb + (size_t)(n0 + g * 64 + lr2) * KK + ch;

  f32x4 acc[8][4] = {};
  constexpr int NS = KK / 64;

  // prologue: stage slice 0, drain, barrier
  {
    __bf16* slot = lds;
    #pragma unroll
    for (int g = 0; g < 4; ++g)
      async_copy16(aP[g], slot + g * 4096 + wave * 512);
    #pragma unroll
    for (int g = 0; g < 4; ++g)
      async_copy16(bP[g], slot + 16384 + g * 4096 + wave * 512);
  }
  asm volatile("s_waitcnt vmcnt(0)" ::: "memory");
  __builtin_amdgcn_s_barrier();

  const int arow0 = (wr << 7) + lrow;          // + (mh*4+mi)*16
  const int brow0 = (wc << 6) + lrow;          // + ni*16

  for (int s = 0; s < NS; ++s) {
    // issue next slice's stages at slice TOP (max latency slack before boundary wait)
    if (s + 1 < NS) {
      __bf16* slot = lds + (((s + 1) & 1) << 15);
      const int ko = (s + 1) * 64;
      #pragma unroll
      for (int g = 0; g < 4; ++g)
        async_copy16(aP[g] + ko, slot + g * 4096 + wave * 512);
      #pragma unroll
      for (int g = 0; g < 4; ++g)
        async_copy16(bP[g] + ko, slot + 16384 + g * 4096 + wave * 512);
    }
    const __bf16* Asl = lds + ((s & 1) << 15);
    const __bf16* Bsl = Asl + 16384;
    #pragma unroll
    for (int kh = 0; kh < 2; ++kh) {
      const int sw = kh ? sw1 : sw0;
      bf16x8 bfr[4];
      #pragma unroll
      for (int ni = 0; ni < 4; ++ni)
        bfr[ni] = *(const bf16x8*)(Bsl + ((brow0 + ni * 16) << 6) + sw);
      #pragma unroll
      for (int mh = 0; mh < 2; ++mh) {
        bf16x8 af[4];
        #pragma unroll
        for (int mi = 0; mi < 4; ++mi)
          af[mi] = *(const bf16x8*)(Asl + ((arow0 + (mh * 4 + mi) * 16) << 6) + sw);
        __builtin_amdgcn_s_setprio(1);
        #pragma unroll
        for (int mi = 0; mi < 4; ++mi)
          #pragma unroll
          for (int ni = 0; ni < 4; ++ni)
            acc[mh * 4 + mi][ni] =
                __builtin_amdgcn_mfma_f32_16x16x32_bf16(af[mi], bfr[ni], acc[mh * 4 + mi][ni], 0, 0, 0);
        __builtin_amdgcn_s_setprio(0);
      }
    }
    if (s + 1 < NS) {   // slice boundary: next slice landed for ALL waves; ring slot (s&1) free
      asm volatile("s_waitcnt vmcnt(0)" ::: "memory");
      __builtin_amdgcn_s_barrier();
    }
  }

  if (MODE == 0) {
    __bf16* O = (__bf16*)Cout + (size_t)e * NTOK * NN;
    #pragma unroll
    for (int mi = 0; mi < 8; ++mi) {
      #pragma unroll
      for (int r = 0; r < 4; ++r) {
        const int row = m0 + (wr << 7) + mi * 16 + (quad << 2) + r;   // packed row, < 4096
        const float sv = inv_num[pe[min(row, Me - 1)]];
        #pragma unroll
        for (int ni = 0; ni < 4; ++ni) {
          const int col = n0 + (wc << 6) + ni * 16 + lrow;
          O[(size_t)row * NN + col] = (__bf16)(gelu_f(acc[mi][ni][r]) * sv);
        }
      }
    }
  } else {
    float* O = (float*)Cout;
    #pragma unroll
    for (int mi = 0; mi < 8; ++mi) {
      #pragma unroll
      for (int r = 0; r < 4; ++r) {
        const int row = m0 + (wr << 7) + mi * 16 + (quad << 2) + r;
        if (row < Me) {
          const int tok = pe[row];
          #pragma unroll
          for (int ni = 0; ni < 4; ++ni) {
            const int col = n0 + (wc << 6) + ni * 16 + lrow;
            atomicAdd(&O[(size_t)tok * NN + col], acc[mi][ni][r]);
          }
        }
      }
    }
  }
}

extern "C" void kernel_launch(void* const* d_in, const int* in_sizes, int n_in,
                              void* d_out, int out_size, void* d_ws, size_t ws_size,
                              hipStream_t stream) {
  (void)in_sizes; (void)n_in; (void)out_size; (void)ws_size;
  const float* h     = (const float*)d_in[0];
  const float* sim   = (const float*)d_in[1];
  const float* gates = (const float*)d_in[2];
  const float* temp  = (const float*)d_in[3];
  const float* emask = (const float*)d_in[4];
  const float* w1    = (const float*)d_in[5];
  const float* w2    = (const float*)d_in[6];
  const int*   minexp = (const int*)d_in[7];

  float* out_final  = (float*)d_out;                        // [4096][1024]
  float* out_logits = out_final + (size_t)NTOK * CDIM;      // [4096][8]
  float* out_act    = out_logits + (size_t)NTOK * EEXP;     // [4096][8]

  char* ws = (char*)d_ws;                                   // ~200.1 MB used (ws >= 209846528 proven r3)
  float*          inv_num  = (float*)(ws + 0);              // [4096] f32 (16KB)
  int*            counts   = (int*)(ws + 16384);            // [8] i32
  unsigned short* perm     = (unsigned short*)(ws + 16448); // [8][4096] u16 (64KB)
  __bf16*         hb       = (__bf16*)(ws + 81984);         // [4096][1024] bf16 (8MB)
  __bf16*         w1T_all  = (__bf16*)(ws + 8470592);       // [E][2048][1024] bf16 (32MB)
  __bf16*         w2T_all  = (__bf16*)(ws + 42025024);      // [E][1024][2048] bf16 (32MB)
  __bf16*         inter_pk = (__bf16*)(ws + 75579456);      // [E][4096][2048] bf16 (128MB)

  const long sW = (long)CDIM * IDIM;

  hipMemsetAsync(out_final, 0, (size_t)NTOK * CDIM * sizeof(float), stream);
  // w1[e]: [C][I] f32 -> w1T [I][C] bf16;  w2[e]: [I][C] f32 -> w2T [C][I] bf16
  transpose_f32_bf16<<<dim3(IDIM / 64, CDIM / 64, EEXP), 256, 0, stream>>>(
      w1, w1T_all, CDIM, IDIM, sW, sW);
  transpose_f32_bf16<<<dim3(CDIM / 64, IDIM / 64, EEXP), 256, 0, stream>>>(
      w2, w2T_all, IDIM, CDIM, sW, sW);
  gating_kernel<<<NTOK, 256, 0, stream>>>(h, sim, gates, temp, emask, minexp,
                                          out_logits, out_act, inv_num, hb);
  pack_kernel<<<EEXP, 64, 0, stream>>>(out_act, counts, perm);
  // gemm1 (packed, 256^2 BK=64 ring-2): inter_pk[e][0..Me) = gelu(hb[perm] @ w1[e]) * inv_num[perm]
  gemm_pk<0, IDIM, CDIM, IDIM / 256><<<dim3((IDIM / 256) * (NTOK / 256) * EEXP), 512, 0, stream>>>(
      hb, w1T_all, counts, perm, inv_num, (void*)inter_pk);
  // gemm2 (packed, 256^2 BK=64 ring-2): out[perm] += inter_pk[e] @ w2[e]
  gemm_pk<1, CDIM, IDIM, CDIM / 256><<<dim3((CDIM / 256) * (NTOK / 256) * EEXP), 512, 0, stream>>>(
      inter_pk, w2T_all, counts, perm, inv_num, (void*)out_final);
}

// Round 5
// 473.132 us; speedup vs baseline: 1.0764x; 1.0577x over previous
//
#include <hip/hip_runtime.h>
#include <math.h>

typedef __bf16 bf16x8 __attribute__((ext_vector_type(8)));
typedef __bf16 bf16x4 __attribute__((ext_vector_type(4)));
typedef float  f32x4  __attribute__((ext_vector_type(4)));

#define NTOK 4096
#define CDIM 1024
#define EEXP 8
#define IDIM 2048

__device__ __forceinline__ void async_copy16(const __bf16* g, __bf16* l) {
  __builtin_amdgcn_global_load_lds((const __attribute__((address_space(1))) void*)g,
                                   (__attribute__((address_space(3))) void*)l,
                                   16, 0, 0);
}

// tanh-form gelu: max abs dev from exact erf-gelu ~3e-4
__device__ __forceinline__ float gelu_f(float x) {
  float u = 0.7978845608028654f * fmaf(0.044715f * x * x, x, x);
  float ex = __expf(-2.f * fabsf(u));
  float th = copysignf((1.f - ex) / (1.f + ex), u);
  return 0.5f * x * (1.f + th);
}

// ---------------- gating + h->bf16 (one block per token; NO atomics) ----------------
__global__ __launch_bounds__(256) void gating_kernel(
    const float* __restrict__ h, const float* __restrict__ sim,
    const float* __restrict__ gates, const float* __restrict__ temp,
    const float* __restrict__ emask, const int* __restrict__ minexp,
    float* __restrict__ out_logits, float* __restrict__ out_act,
    float* __restrict__ inv_num, __bf16* __restrict__ hb)
{
  const int t = blockIdx.x, tid = threadIdx.x;
  float4 hv4 = ((const float4*)(h + (size_t)t * CDIM))[tid];
  float hv[4] = {hv4.x, hv4.y, hv4.z, hv4.w};
  bf16x4 hb4 = {(__bf16)hv[0], (__bf16)hv[1], (__bf16)hv[2], (__bf16)hv[3]};
  ((bf16x4*)(hb + (size_t)t * CDIM))[tid] = hb4;

  float d[EEXP], nn[EEXP];
  #pragma unroll
  for (int e = 0; e < EEXP; ++e) { d[e] = 0.f; nn[e] = 0.f; }
  float ss = 0.f;
  #pragma unroll
  for (int j = 0; j < 4; ++j) {
    ss = fmaf(hv[j], hv[j], ss);
    const float* sr = sim + (size_t)(tid * 4 + j) * EEXP;  // one sim row = 8 f32
    float4 s0 = ((const float4*)sr)[0];
    float4 s1 = ((const float4*)sr)[1];
    float sv[8] = {s0.x, s0.y, s0.z, s0.w, s1.x, s1.y, s1.z, s1.w};
    #pragma unroll
    for (int e = 0; e < EEXP; ++e) {
      d[e]  = fmaf(hv[j], sv[e], d[e]);
      nn[e] = fmaf(sv[e], sv[e], nn[e]);
    }
  }
  #pragma unroll
  for (int off = 32; off > 0; off >>= 1) {
    ss += __shfl_down(ss, off);
    #pragma unroll
    for (int e = 0; e < EEXP; ++e) {
      d[e]  += __shfl_down(d[e], off);
      nn[e] += __shfl_down(nn[e], off);
    }
  }
  __shared__ float red[4][20];
  const int wv = tid >> 6;
  if ((tid & 63) == 0) {
    red[wv][0] = ss;
    #pragma unroll
    for (int e = 0; e < EEXP; ++e) { red[wv][1 + e] = d[e]; red[wv][9 + e] = nn[e]; }
  }
  __syncthreads();
  if (tid == 0) {
    float sst = red[0][0] + red[1][0] + red[2][0] + red[3][0];
    float inv_h = 1.f / fmaxf(sqrtf(sst), 1e-12f);
    float ls = 1.f / (1.f + expf(-temp[0]));
    float logit[EEXP], act[EEXP];
    float cnt = 0.f;
    #pragma unroll
    for (int e = 0; e < EEXP; ++e) {
      float dot = red[0][1 + e] + red[1][1 + e] + red[2][1 + e] + red[3][1 + e];
      float nne = red[0][9 + e] + red[1][9 + e] + red[2][9 + e] + red[3][9 + e];
      float inv_s = 1.f / fmaxf(sqrtf(nne), 1e-12f);
      logit[e] = dot * inv_h * inv_s * emask[e];
      float g = logit[e] - gates[e] * ls;   // relu(x)>0 <=> x>0
      act[e] = (g > 0.f) ? 1.f : 0.f;
      cnt += act[e];
    }
    if (cnt == 0.f) {  // fallback: top-min_experts by logits (ties -> lowest index)
      int k = minexp[0];
      if (k > EEXP) k = EEXP;
      bool used[EEXP];
      #pragma unroll
      for (int e = 0; e < EEXP; ++e) used[e] = false;
      for (int j = 0; j < k; ++j) {
        int best = -1; float bv = 0.f;
        for (int e = 0; e < EEXP; ++e)
          if (!used[e] && (best < 0 || logit[e] > bv)) { best = e; bv = logit[e]; }
        if (best >= 0) { used[best] = true; act[best] = 1.f; cnt += 1.f; }
      }
    }
    float num = fmaxf(cnt, 1.f);
    inv_num[t] = 1.f / num;
    #pragma unroll
    for (int e = 0; e < EEXP; ++e) {
      out_logits[(size_t)t * EEXP + e] = logit[e];
      out_act[(size_t)t * EEXP + e]   = act[e];
    }
  }
}

// ---------------- pack: one wave per expert, ballot prefix scan (no atomics) ----------------
__global__ __launch_bounds__(64) void pack_kernel(
    const float* __restrict__ out_act, int* __restrict__ counts,
    unsigned short* __restrict__ perm)
{
  const int e = blockIdx.x;
  const int lane = threadIdx.x;
  const unsigned long long ltmask = (lane == 63) ? ~0ULL >> 1 : (1ULL << lane) - 1ULL;
  int base = 0;
  for (int i = 0; i < NTOK / 64; ++i) {
    int tok = i * 64 + lane;
    bool f = out_act[(size_t)tok * EEXP + e] > 0.f;
    unsigned long long m = __ballot(f);
    if (f) perm[e * NTOK + base + __popcll(m & ltmask)] = (unsigned short)tok;
    base += __popcll(m);
  }
  if (lane == 0) counts[e] = base;
}

// ---------------- fp32 64x64 tiled transpose+convert: out_bf16[c][r] = in_f32[r][c] ----------------
__global__ __launch_bounds__(256) void transpose_f32_bf16(
    const float* __restrict__ in0, __bf16* __restrict__ out0, int R, int Cc,
    long sIn, long sOut)
{
  const float* in = in0 + (size_t)blockIdx.z * sIn;
  __bf16* out = out0 + (size_t)blockIdx.z * sOut;
  __shared__ __align__(16) __bf16 tile[64][72];
  const int tid = threadIdx.x;
  const int c0 = blockIdx.x * 64, r0 = blockIdx.y * 64;
  #pragma unroll
  for (int p = 0; p < 2; ++p) {
    int lin = p * 256 + tid;
    int r = lin >> 3, c8 = (lin & 7) * 8;
    const float* src = in + (size_t)(r0 + r) * Cc + c0 + c8;
    float4 v0 = ((const float4*)src)[0];
    float4 v1 = ((const float4*)src)[1];
    bf16x8 v = {(__bf16)v0.x, (__bf16)v0.y, (__bf16)v0.z, (__bf16)v0.w,
                (__bf16)v1.x, (__bf16)v1.y, (__bf16)v1.z, (__bf16)v1.w};
    *(bf16x8*)&tile[r][c8] = v;
  }
  __syncthreads();
  #pragma unroll
  for (int p = 0; p < 2; ++p) {
    int lin = p * 256 + tid;
    int oc = lin >> 3, j8 = (lin & 7) * 8;
    bf16x8 o;
    #pragma unroll
    for (int jj = 0; jj < 8; ++jj) o[jj] = tile[j8 + jj][oc];
    *(bf16x8*)(out + (size_t)(c0 + oc) * R + r0 + j8) = o;
  }
}

// ---------------- 256x256-tile 8-wave packed GEMM, kh-split 4-phase counted-vmcnt ----------------
// T3+T4 (m201/m218): LDS regions split by K-half (A-kh0/A-kh1/B-kh0/B-kh1, 16KB contiguous each)
// so staging granularity = (operand, kh). kh0 of tile t is dead after phase1 -> tile t+2's kh0
// stages into the SAME slot during tile t phases 2/3. Steady state: 12 loads in flight,
// s_waitcnt vmcnt(8) at phase-1/3 ends -- NEVER 0 until the final tiles.
// Per phase: {4-8 ds_read || 2 global_load_lds -> setprio(1) 16 MFMA setprio(0) -> barrier}.
// T2: paired-row 3-bit XOR swizzle on 64B rows (2-way residual = free). Involution on both sides.
// T5: setprio. T1: XCD panel decode.
// MODE 0 (gemm1): A = hb gathered via perm[e]; epilogue gelu*inv_num -> bf16 inter_pk[e]
// MODE 1 (gemm2): A = inter_pk[e] packed rows; epilogue atomicAdd scatter to out f32 by token
template <int MODE, int NN, int KK, int NB>
__global__ __launch_bounds__(512, 2) void gemm_pk(
    const __bf16* __restrict__ A0, const __bf16* __restrict__ B0,
    const int* __restrict__ counts, const unsigned short* __restrict__ perm,
    const float* __restrict__ inv_num, void* __restrict__ Cout)
{
  // XCD-aware decode: h = xr + 8*(g*16 + mb), panel = g*8 + xr -> (e, nb)
  const int hid = blockIdx.x;
  const int xr = hid & 7, q2 = hid >> 3;
  const int mb = q2 & 15;
  const int panel = ((q2 >> 4) << 3) + xr;
  const int e = panel / NB;
  const int nb = panel - e * NB;
  const int Me = counts[e];
  const int m0 = mb * 256;
  if (m0 >= Me) return;                       // block-uniform, before any barrier
  const int n0 = nb * 256;

  const int tid = threadIdx.x;
  const int wave = tid >> 6, lane = tid & 63;
  const int wr = wave >> 2, wc = wave & 3;    // 2M x 4N wave grid; wave owns 128x64
  const int quad = lane >> 4, lrow = lane & 15;

  // LDS: 2 slots x [Akh0|Akh1|Bkh0|Bkh1], each region 256x32 bf16 = 16KB (contiguous).
  // Region physical rows = 128B = 2 logical rows; 16B slot index s=(r&1)*4+c, phys = s^((r>>1)&7).
  __shared__ __align__(16) __bf16 lds[2 * 32768];

  // ---- read-side swizzled offsets (element units) ----
  // A frag row r = wr*128 + mh*64 + mi*16 + lrow; B frag row r = wc*64 + ni*16 + lrow.
  // (r>>1)&7 == (lrow>>1)&7 for all frags (other terms are multiples of 8).
  const int sphys = (((lrow & 1) << 2) | quad) ^ ((lrow >> 1) & 7);
  const int aro = ((((wr << 6) + (lrow >> 1)) << 6) + (sphys << 3));  // + mh*2048 + mi*512
  const int bro = ((((wc << 5) + (lrow >> 1)) << 6) + (sphys << 3));  // + ni*512

  // ---- staging source mapping (inverse swizzle) ----
  // Call j writes region phys elems [j*4096 + wave*512 + lane*8): Rp=j*64+wave*8+(lane>>3),
  // sp=lane&7 -> logical s = sp^(lane>>3), row = j*128 + wave*16 + (lane>>3)*2 + (s>>2), col c=(s&3)*8.
  const int sst = (lane & 7) ^ (lane >> 3);
  const int rb  = (wave << 4) + ((lane >> 3) << 1) + (sst >> 2);  // row for j=0; +128 for j=1
  const int cch = (sst & 3) << 3;                                 // col elem offset within kh-half
  const unsigned short* pe = perm + e * NTOK;
  const __bf16 *aG0, *aG1;
  if (MODE == 0) {
    aG0 = A0 + (size_t)pe[min(m0 + rb, Me - 1)] * KK + cch;
    aG1 = A0 + (size_t)pe[min(m0 + 128 + rb, Me - 1)] * KK + cch;
  } else {
    const __bf16* Ab = A0 + (size_t)e * NTOK * KK;
    aG0 = Ab + (size_t)(m0 + rb) * KK + cch;
    aG1 = Ab + (size_t)(m0 + 128 + rb) * KK + cch;
  }
  const __bf16* Bb = B0 + (size_t)e * ((size_t)CDIM * IDIM);
  const __bf16* bG0 = Bb + (size_t)(n0 + rb) * KK + cch;
  const __bf16* bG1 = Bb + (size_t)(n0 + 128 + rb) * KK + cch;

#define STAGE_A(tt, khh) do { \
    __bf16* _d = lds + (((tt) & 1) << 15) + ((khh) << 13) + (wave << 9); \
    const size_t _co = (size_t)(tt) * 64 + (khh) * 32; \
    async_copy16(aG0 + _co, _d); \
    async_copy16(aG1 + _co, _d + 4096); \
  } while (0)
#define STAGE_B(tt, khh) do { \
    __bf16* _d = lds + (((tt) & 1) << 15) + 16384 + ((khh) << 13) + (wave << 9); \
    const size_t _co = (size_t)(tt) * 64 + (khh) * 32; \
    async_copy16(bG0 + _co, _d); \
    async_copy16(bG1 + _co, _d + 4096); \
  } while (0)
#define MFMA16(base) do { \
    __builtin_amdgcn_s_setprio(1); \
    _Pragma("unroll") \
    for (int mi = 0; mi < 4; ++mi) \
      _Pragma("unroll") \
      for (int ni = 0; ni < 4; ++ni) \
        acc[(base) + mi][ni] = __builtin_amdgcn_mfma_f32_16x16x32_bf16(af[mi], bfr[ni], acc[(base) + mi][ni], 0, 0, 0); \
    __builtin_amdgcn_s_setprio(0); \
  } while (0)

  f32x4 acc[8][4] = {};
  constexpr int NS = KK / 64;

  // prologue: (0,kh0)A,B ; (0,kh1)A,B ; (1,kh0)A,B  = 12 loads; wait oldest 4 -> tile0 kh0 in.
  STAGE_A(0, 0); STAGE_B(0, 0);
  STAGE_A(0, 1); STAGE_B(0, 1);
  STAGE_A(1, 0); STAGE_B(1, 0);
  asm volatile("s_waitcnt vmcnt(8)" ::: "memory");
  __builtin_amdgcn_s_barrier();

  for (int t = 0; t < NS; ++t) {
    const __bf16* SA0 = lds + ((t & 1) << 15);
    const __bf16* SA1 = SA0 + 8192;
    const __bf16* SBk0 = SA0 + 16384;
    const __bf16* SBk1 = SA0 + 24576;
    bf16x8 af[4], bfr[4];
    // ---- P0: (mh0, kh0); stage (t+1, A, kh1) ----
    #pragma unroll
    for (int ni = 0; ni < 4; ++ni) bfr[ni] = *(const bf16x8*)(SBk0 + bro + ni * 512);
    #pragma unroll
    for (int mi = 0; mi < 4; ++mi) af[mi] = *(const bf16x8*)(SA0 + aro + mi * 512);
    if (t + 1 < NS) STAGE_A(t + 1, 1);
    MFMA16(0);
    __builtin_amdgcn_s_barrier();
    // ---- P1: (mh1, kh0); stage (t+1, B, kh1); counted wait ----
    #pragma unroll
    for (int mi = 0; mi < 4; ++mi) af[mi] = *(const bf16x8*)(SA0 + aro + 2048 + mi * 512);
    if (t + 1 < NS) STAGE_B(t + 1, 1);
    MFMA16(4);
    if (t + 1 < NS) { asm volatile("s_waitcnt vmcnt(8)" ::: "memory"); }
    else            { asm volatile("s_waitcnt vmcnt(0)" ::: "memory"); }
    __builtin_amdgcn_s_barrier();
    // ---- P2: (mh0, kh1); stage (t+2, A, kh0) into SAME slot (kh0 dead since P1) ----
    #pragma unroll
    for (int ni = 0; ni < 4; ++ni) bfr[ni] = *(const bf16x8*)(SBk1 + bro + ni * 512);
    #pragma unroll
    for (int mi = 0; mi < 4; ++mi) af[mi] = *(const bf16x8*)(SA1 + aro + mi * 512);
    if (t + 2 < NS) STAGE_A(t + 2, 0);
    MFMA16(0);
    __builtin_amdgcn_s_barrier();
    // ---- P3: (mh1, kh1); stage (t+2, B, kh0); counted wait ----
    #pragma unroll
    for (int mi = 0; mi < 4; ++mi) af[mi] = *(const bf16x8*)(SA1 + aro + 2048 + mi * 512);
    if (t + 2 < NS) STAGE_B(t + 2, 0);
    MFMA16(4);
    if (t + 2 < NS)      { asm volatile("s_waitcnt vmcnt(8)" ::: "memory"); }
    else if (t + 1 < NS) { asm volatile("s_waitcnt vmcnt(4)" ::: "memory"); }
    __builtin_amdgcn_s_barrier();
  }
#undef STAGE_A
#undef STAGE_B
#undef MFMA16

  if (MODE == 0) {
    __bf16* O = (__bf16*)Cout + (size_t)e * NTOK * NN;
    #pragma unroll
    for (int mi = 0; mi < 8; ++mi) {
      #pragma unroll
      for (int r = 0; r < 4; ++r) {
        const int row = m0 + (wr << 7) + mi * 16 + (quad << 2) + r;   // packed row, < 4096
        const float sv = inv_num[pe[min(row, Me - 1)]];
        #pragma unroll
        for (int ni = 0; ni < 4; ++ni) {
          const int col = n0 + (wc << 6) + ni * 16 + lrow;
          O[(size_t)row * NN + col] = (__bf16)(gelu_f(acc[mi][ni][r]) * sv);
        }
      }
    }
  } else {
    float* O = (float*)Cout;
    #pragma unroll
    for (int mi = 0; mi < 8; ++mi) {
      #pragma unroll
      for (int r = 0; r < 4; ++r) {
        const int row = m0 + (wr << 7) + mi * 16 + (quad << 2) + r;
        if (row < Me) {
          const int tok = pe[row];
          #pragma unroll
          for (int ni = 0; ni < 4; ++ni) {
            const int col = n0 + (wc << 6) + ni * 16 + lrow;
            atomicAdd(&O[(size_t)tok * NN + col], acc[mi][ni][r]);
          }
        }
      }
    }
  }
}

extern "C" void kernel_launch(void* const* d_in, const int* in_sizes, int n_in,
                              void* d_out, int out_size, void* d_ws, size_t ws_size,
                              hipStream_t stream) {
  (void)in_sizes; (void)n_in; (void)out_size; (void)ws_size;
  const float* h     = (const float*)d_in[0];
  const float* sim   = (const float*)d_in[1];
  const float* gates = (const float*)d_in[2];
  const float* temp  = (const float*)d_in[3];
  const float* emask = (const float*)d_in[4];
  const float* w1    = (const float*)d_in[5];
  const float* w2    = (const float*)d_in[6];
  const int*   minexp = (const int*)d_in[7];

  float* out_final  = (float*)d_out;                        // [4096][1024]
  float* out_logits = out_final + (size_t)NTOK * CDIM;      // [4096][8]
  float* out_act    = out_logits + (size_t)NTOK * EEXP;     // [4096][8]

  char* ws = (char*)d_ws;                                   // ~200.1 MB used (ws >= 209846528 proven r3)
  float*          inv_num  = (float*)(ws + 0);              // [4096] f32 (16KB)
  int*            counts   = (int*)(ws + 16384);            // [8] i32
  unsigned short* perm     = (unsigned short*)(ws + 16448); // [8][4096] u16 (64KB)
  __bf16*         hb       = (__bf16*)(ws + 81984);         // [4096][1024] bf16 (8MB)
  __bf16*         w1T_all  = (__bf16*)(ws + 8470592);       // [E][2048][1024] bf16 (32MB)
  __bf16*         w2T_all  = (__bf16*)(ws + 42025024);      // [E][1024][2048] bf16 (32MB)
  __bf16*         inter_pk = (__bf16*)(ws + 75579456);      // [E][4096][2048] bf16 (128MB)

  const long sW = (long)CDIM * IDIM;

  hipMemsetAsync(out_final, 0, (size_t)NTOK * CDIM * sizeof(float), stream);
  // w1[e]: [C][I] f32 -> w1T [I][C] bf16;  w2[e]: [I][C] f32 -> w2T [C][I] bf16
  transpose_f32_bf16<<<dim3(IDIM / 64, CDIM / 64, EEXP), 256, 0, stream>>>(
      w1, w1T_all, CDIM, IDIM, sW, sW);
  transpose_f32_bf16<<<dim3(CDIM / 64, IDIM / 64, EEXP), 256, 0, stream>>>(
      w2, w2T_all, IDIM, CDIM, sW, sW);
  gating_kernel<<<NTOK, 256, 0, stream>>>(h, sim, gates, temp, emask, minexp,
                                          out_logits, out_act, inv_num, hb);
  pack_kernel<<<EEXP, 64, 0, stream>>>(out_act, counts, perm);
  // gemm1 (packed, kh-split counted-vmcnt): inter_pk[e][0..Me) = gelu(hb[perm] @ w1[e]) * inv_num
  gemm_pk<0, IDIM, CDIM, IDIM / 256><<<dim3((IDIM / 256) * (NTOK / 256) * EEXP), 512, 0, stream>>>(
      hb, w1T_all, counts, perm, inv_num, (void*)inter_pk);
  // gemm2 (packed, kh-split counted-vmcnt): out[perm] += inter_pk[e] @ w2[e]
  gemm_pk<1, CDIM, IDIM, CDIM / 256><<<dim3((CDIM / 256) * (NTOK / 256) * EEXP), 512, 0, stream>>>(
      inter_pk, w2T_all, counts, perm, inv_num, (void*)out_final);
}